// Round 1
// baseline (326.625 us; speedup 1.0000x reference)
//
#include <hip/hip_runtime.h>
#include <hip/hip_bf16.h>
#include <math.h>

typedef __hip_bfloat16 bf16;

#define NNODES 20000
#define NEDGES 320000
#define DLEN   16
#define G      64
#define DW     300
#define DH     256
#define HD     128
#define G3     384
#define NCLS   2000
#define NB     4
#define TT     32
#define VDESC  30000
#define NPART  5000   // k_agg blocks, 4 nodes each -> one attn2 partial per block
#define A2MID  64     // stage-1 merge outputs

#define NBLK_CVT   384
#define NBLK_GX2   1536   // 256 rows (d,b,step) x 6 j-tiles of 64
#define NBLK_DESCB (VDESC / 16)            // 1875
#define NBLK_HIST  ((NEDGES + 255) / 256)
#define NBLK_W2T   (32 * 16)               // 32 c-tiles x 16 u-tiles of 64
#define NBLK_SCAT  ((NEDGES + 255) / 256)
#define NBLK_A1    (NNODES / 16)           // 1250, 16 nodes per block
#define NBLK_DQ    ((VDESC + 63) / 64)     // 469

__device__ __forceinline__ float ld(const float* p, size_t i) { return p[i]; }
__device__ __forceinline__ float ld(const bf16* p, size_t i) { return __bfloat162float(p[i]); }
__device__ __forceinline__ void st(float* p, size_t i, float v) { p[i] = v; }
__device__ __forceinline__ void st(bf16* p, size_t i, float v) { p[i] = __float2bfloat16(v); }
__device__ __forceinline__ float relu(float x) { return (x < 0.f) ? 0.f : x; }

// ---------------- workspace layout (float words) ----------------
#define OFF_FLAG  ((size_t)0)                         // 4
#define OFF_GX    (OFF_FLAG + 4)                      // 98304
#define OFF_WHF   (OFF_GX   + 2*NB*TT*G3)             // 98304
#define OFF_QEMB  (OFF_WHF  + 2*HD*G3)                // 1024
#define OFF_QG    (OFF_QEMB + NB*DH)                  // 256
#define OFF_HB    (OFF_QG   + NB*G)                   // bf16 [n][b][g] = 2.56M words
#define OFF_DESCB (OFF_HB   + (size_t)NB*NNODES*G/2)  // bf16 30000*64 = 960000 words
#define OFF_DQ    (OFF_DESCB + (size_t)VDESC*G/2)     // fp32 30000*4 = 120000
#define OFF_PART  (OFF_DQ   + (size_t)VDESC*NB)       // 5000*4*66
#define OFF_PART2 (OFF_PART + (size_t)NPART*NB*66)    // 64*4*66
#define OFF_DEG   (OFF_PART2+ (size_t)A2MID*NB*66)    // int 20000
#define OFF_OFFS  (OFF_DEG  + NNODES)                 // int 20008
#define OFF_RANK  (OFF_OFFS + NNODES + 8)             // int 320000
#define OFF_EPACK (OFF_RANK + NEDGES)                 // int2 x 320000 (word idx even)
#define OFF_HID   (OFF_EPACK + 2*(size_t)NEDGES)      // 4096
#define OFF_W2T   (OFF_HID  + 4096)                   // fp32 2000*1024 = 2048000

// ---------------- init: dtype sniff + zero deg ----------------
__global__ void k_init(const unsigned* probe, int* flag, int* deg) {
    int i = blockIdx.x * 256 + threadIdx.x;
    if (i < NNODES) deg[i] = 0;
    if (blockIdx.x == 0 && threadIdx.x < 64) {
        int cnt = 0;
        for (int k = threadIdx.x; k < 4096; k += 64) {
            unsigned lo = probe[k] & 0xFFFFu;
            unsigned e = (lo >> 7) & 0xFFu;
            cnt += (e >= 0x66u && e <= 0x7Eu) ? 1 : 0;
        }
#pragma unroll
        for (int off = 1; off < 64; off <<= 1) cnt += __shfl_xor(cnt, off, 64);
        if (threadIdx.x == 0) *flag = (2 * cnt > 4096) ? 1 : 0;   // 1 = bf16
    }
}

// ---------------- fused prep: cvt | gx | descB | hist | W2 transpose -------
template <typename T>
__device__ void cvt_body(int id, const void* Whf_, const void* Whb_, float* whf) {
    if (id >= 2 * HD * G3) return;
    int d = id / (HD * G3), r = id % (HD * G3);
    const T* W = (const T*)(d ? Whb_ : Whf_);
    whf[id] = ld(W, (size_t)r);
}

template <typename T>
__device__ void gx2_body(int bx2, const int* questions, const void* emb_word_,
                         const void* Wxf_, const void* bxf_,
                         const void* Wxb_, const void* bxb_, float* gx,
                         float* xs, float* psum) {
    int tid = threadIdx.x;
    int jt = bx2 % 6;
    int rid = bx2 / 6;                  // 0..255
    int step = rid & 31;
    int b = (rid >> 5) & 3;
    int d = rid >> 7;
    int t = d ? (TT - 1 - step) : step;
    int tok = questions[b * TT + t];
    const T* row = (const T*)emb_word_ + (size_t)tok * DW;
    for (int k = tid; k < DW; k += 256) xs[k] = ld(row, (size_t)k);
    __syncthreads();
    int lane = tid & 63, phase = tid >> 6;
    int j = jt * 64 + lane;
    const T* Wx = (const T*)(d ? Wxb_ : Wxf_);
    float acc = 0.f;
    int k0 = phase * 75;
#pragma unroll 15
    for (int kk = 0; kk < 75; kk++) {
        int k = k0 + kk;
        acc += xs[k] * ld(Wx, (size_t)k * G3 + j);
    }
    psum[tid] = acc;
    __syncthreads();
    if (phase == 0) {
        const T* bx = (const T*)(d ? bxb_ : bxf_);
        float tot = ld(bx, (size_t)j)
                  + psum[lane] + psum[64 + lane] + psum[128 + lane] + psum[192 + lane];
        gx[(size_t)rid * G3 + j] = tot;
    }
}

// descB[idx][g] = sum_k emb_desc[idx][k] * bases[k][g]; 16 rows per block.
template <typename T>
__device__ void descb_body(int bx3, const void* emb_desc_, const void* bases_,
                           bf16* descB, float* bsm, float* rsm) {
    int tid = threadIdx.x;
    const T* bases = (const T*)bases_;
    const T* desc = (const T*)emb_desc_;
    for (int i = tid; i < G * G; i += 256) bsm[(i >> 6) * 68 + (i & 63)] = ld(bases, (size_t)i);
    int r0 = bx3 * 16;
    for (int i = tid; i < 16 * G; i += 256) {
        int r = i >> 6, k = i & 63;
        rsm[r * 68 + k] = ld(desc, (size_t)(r0 + r) * G + k);
    }
    __syncthreads();
    int g = tid & 63, slot = tid >> 6;
#pragma unroll
    for (int it = 0; it < 4; it++) {
        int r = slot * 4 + it;
        float acc = 0.f;
#pragma unroll 8
        for (int k = 0; k < G; k++) acc = fmaf(rsm[r * 68 + k], bsm[k * 68 + g], acc);
        descB[(size_t)(r0 + r) * G + g] = __float2bfloat16(acc);
    }
}

// transpose W2 [1024][2000] -> W2T fp32 [2000][1024] (exact copy, row-major reads in fc2)
template <typename T>
__device__ void w2t_body(int bx5, const void* W2_, float* w2t, float* tile /*64*65*/) {
    int tid = threadIdx.x;
    int ct = bx5 >> 4, ut = bx5 & 15;
    int c0 = ct * 64, u0 = ut * 64;
    int lane = tid & 63, slot = tid >> 6;
    const T* W2 = (const T*)W2_;
    int c = c0 + lane;
    bool okc = (c < NCLS);
#pragma unroll
    for (int i = 0; i < 16; i++) {
        int u = slot * 16 + i;
        tile[u * 65 + lane] = okc ? ld(W2, (size_t)(u0 + u) * NCLS + c) : 0.f;
    }
    __syncthreads();
#pragma unroll
    for (int i = 0; i < 16; i++) {
        int cl = slot * 16 + i;
        if (c0 + cl < NCLS)
            w2t[(size_t)(c0 + cl) * 1024 + u0 + lane] = tile[lane * 65 + cl];
    }
}

__global__ void k_prep(const int* flag, const void* Whf, const void* Whb, float* whf,
                       const int* questions, const void* emb_word,
                       const void* Wxf, const void* bxf,
                       const void* Wxb, const void* bxb, float* gx,
                       const void* emb_desc, const void* bases, bf16* descB,
                       const int* edge_dst, int* deg, int* rank,
                       const void* W2, float* w2t) {
    __shared__ __align__(16) float smem[64 * 68 + 16 * 68];
    int bx = blockIdx.x;
    int tid = threadIdx.x;
    if (bx < NBLK_CVT) {
        int id = bx * 256 + tid;
        if (*flag) cvt_body<bf16>(id, Whf, Whb, whf);
        else       cvt_body<float>(id, Whf, Whb, whf);
    } else if (bx < NBLK_CVT + NBLK_GX2) {
        int bx2 = bx - NBLK_CVT;
        float* xs = smem;
        float* psum = smem + 320;
        if (*flag) gx2_body<bf16>(bx2, questions, emb_word, Wxf, bxf, Wxb, bxb, gx, xs, psum);
        else       gx2_body<float>(bx2, questions, emb_word, Wxf, bxf, Wxb, bxb, gx, xs, psum);
    } else if (bx < NBLK_CVT + NBLK_GX2 + NBLK_DESCB) {
        int bx3 = bx - NBLK_CVT - NBLK_GX2;
        float* bsm = smem;
        float* rsm = smem + 64 * 68;
        if (*flag) descb_body<bf16>(bx3, emb_desc, bases, descB, bsm, rsm);
        else       descb_body<float>(bx3, emb_desc, bases, descB, bsm, rsm);
    } else if (bx < NBLK_CVT + NBLK_GX2 + NBLK_DESCB + NBLK_HIST) {
        int e = (bx - NBLK_CVT - NBLK_GX2 - NBLK_DESCB) * 256 + tid;
        if (e < NEDGES) rank[e] = atomicAdd(&deg[edge_dst[e]], 1);
    } else {
        int bx5 = bx - NBLK_CVT - NBLK_GX2 - NBLK_DESCB - NBLK_HIST;
        if (*flag) w2t_body<bf16>(bx5, W2, w2t, smem);
        else       w2t_body<float>(bx5, W2, w2t, smem);
    }
}

// ---------------- GRU scan (blocks 0..7) + CSR scan (block 8) --------------
template <typename T>
__device__ void gru_body(const int* questions, const float* gx, const float* whf,
                         const void* bhf_, const void* bhb_, float* qemb,
                         float* hsm, float* ghs) {
    int tid = threadIdx.x;
    int d = blockIdx.x >> 2, b = blockIdx.x & 3;
    int half = tid / G3, j = tid - half * G3;
    const float* wh = whf + (size_t)d * HD * G3 + (size_t)half * 64 * G3 + j;
    float w[64];
#pragma unroll
    for (int m = 0; m < 64; m++) w[m] = wh[(size_t)m * G3];
    const T* bh = (const T*)(d ? bhb_ : bhf_);
    float bhj = (half == 0) ? ld(bh, (size_t)j) : 0.f;
    if (tid < HD) hsm[tid] = 0.f;
    const float* gxb = gx + ((size_t)(d * NB + b)) * TT * G3;
    __syncthreads();
    const float4* h4 = (const float4*)(hsm + half * 64);
    for (int step = 0; step < TT; step++) {
        float acc = bhj;
#pragma unroll
        for (int m4 = 0; m4 < 16; m4++) {
            float4 hp = h4[m4];
            acc = fmaf(hp.x, w[4 * m4 + 0], acc);
            acc = fmaf(hp.y, w[4 * m4 + 1], acc);
            acc = fmaf(hp.z, w[4 * m4 + 2], acc);
            acc = fmaf(hp.w, w[4 * m4 + 3], acc);
        }
        ghs[half * G3 + j] = acc;
        __syncthreads();
        if (tid < HD) {
            const float* gxp = gxb + step * G3;
            int t = d ? (TT - 1 - step) : step;
            bool msk = questions[b * TT + t] != 0;
            float gr = ghs[tid] + ghs[G3 + tid];
            float gz = ghs[HD + tid] + ghs[G3 + HD + tid];
            float gn = ghs[2 * HD + tid] + ghs[G3 + 2 * HD + tid];
            float r = 1.f / (1.f + expf(-(gxp[tid] + gr)));
            float z = 1.f / (1.f + expf(-(gxp[HD + tid] + gz)));
            float n = tanhf(gxp[2 * HD + tid] + r * gn);
            float hn = (1.f - z) * n + z * hsm[tid];
            if (msk) hsm[tid] = hn;
        }
        __syncthreads();
    }
    if (tid < HD) qemb[b * DH + d * HD + tid] = hsm[tid];
}

// exclusive int scan of deg with 768 threads x 27 elems (exact)
__device__ void scan_body(const int* deg, int* offs, int* wtot) {
    int t = threadIdx.x;                 // 0..767
    int lane = t & 63, wave = t >> 6;    // 12 waves
    int c[27];
    int base = t * 27;
    int run = 0;
#pragma unroll
    for (int i = 0; i < 27; i++) {
        int v = (base + i < NNODES) ? deg[base + i] : 0;
        c[i] = run;
        run += v;
    }
    int myrun = run, inc = run;
#pragma unroll
    for (int off = 1; off < 64; off <<= 1) {
        int u = __shfl_up(inc, off, 64);
        if (lane >= off) inc += u;
    }
    if (lane == 63) wtot[wave] = inc;
    __syncthreads();
    if (t == 0) {
        int s = 0;
#pragma unroll
        for (int i = 0; i < 12; i++) { int v = wtot[i]; wtot[i] = s; s += v; }
        offs[NNODES] = s;
    }
    __syncthreads();
    int ebase = wtot[wave] + inc - myrun;
#pragma unroll
    for (int i = 0; i < 27; i++) {
        if (base + i < NNODES) offs[base + i] = ebase + c[i];
    }
}

__global__ __launch_bounds__(2 * G3) void k_gru(const int* flag, const int* questions,
                                                const float* gx, const float* whf,
                                                const void* bhf, const void* bhb, float* qemb,
                                                const int* deg, int* offs) {
    __shared__ __align__(16) float hsm[HD];
    __shared__ float ghs[2 * G3];
    __shared__ int wtot[12];
    if (blockIdx.x < 8) {
        if (*flag) gru_body<bf16>(questions, gx, whf, bhf, bhb, qemb, hsm, ghs);
        else       gru_body<float>(questions, gx, whf, bhf, bhb, qemb, hsm, ghs);
    } else {
        scan_body(deg, offs, wtot);
    }
}

// ---------------- qg (block 0) + dq = emb_desc @ qg^T (blocks 1..) ---------
template <typename T>
__device__ void qg_compute(const float* qemb, const void* W_hg_, const void* b_hg_,
                           float* out /*256*/) {
    int tid = threadIdx.x;
    int b = tid >> 6, g = tid & 63;
    const T* W = (const T*)W_hg_;
    float acc = ld((const T*)b_hg_, (size_t)g);
#pragma unroll 4
    for (int i = 0; i < DH; i++) acc += qemb[b * DH + i] * ld(W, (size_t)i * G + g);
    out[b * G + g] = acc;
}

template <typename T>
__device__ void dq_body(int chunk, const void* emb_desc_, const float* qgs, float* dq) {
    int tid = threadIdx.x;
    int ii = tid >> 2, b = tid & 3;
    int idx = chunk * 64 + ii;
    if (idx >= VDESC) return;
    const T* row = (const T*)emb_desc_ + (size_t)idx * G;
    const float* q = qgs + b * G;
    float acc = 0.f;
#pragma unroll 8
    for (int k = 0; k < G; k++) acc = fmaf(ld(row, (size_t)k), q[k], acc);
    dq[(size_t)idx * NB + b] = acc;
}

__global__ __launch_bounds__(256) void k_qg_dq(const int* flag, const float* qemb,
                                               const void* W_hg, const void* b_hg, float* qg,
                                               const void* emb_desc, float* dq) {
    __shared__ float qgs[NB * G];
    if (blockIdx.x == 0) {
        if (*flag) qg_compute<bf16>(qemb, W_hg, b_hg, qg);
        else       qg_compute<float>(qemb, W_hg, b_hg, qg);
        return;
    }
    // recompute qg locally (bit-identical) then fill a 64-idx dq chunk
    if (*flag) qg_compute<bf16>(qemb, W_hg, b_hg, qgs);
    else       qg_compute<float>(qemb, W_hg, b_hg, qgs);
    __syncthreads();
    int chunk = blockIdx.x - 1;
    if (*flag) dq_body<bf16>(chunk, emb_desc, qgs, dq);
    else       dq_body<float>(chunk, emb_desc, qgs, dq);
}

// ---------------- fused: scatter (no atomics) | attn1 -> hb16 directly -----
template <typename T>
__device__ void scatter_body(int e, const int* src, const int* dst, const int* typ,
                             const void* w_comp_, const int* offs, const int* rank,
                             int2* epack) {
    if (e < NEDGES) {
        int pos = offs[dst[e]] + rank[e];
        int2 v;
        v.x = src[e];
        v.y = __float_as_int(ld((const T*)w_comp_, (size_t)typ[e]));
        epack[pos] = v;
    }
}

__device__ void attn1_body(int nb4, const int* node_descs, const float* dq,
                           const bf16* descB, bf16* hb16, float* attn_s, int* idxs) {
    int tid = threadIdx.x;
    int w = tid >> 6, lane = tid & 63;
    int n = nb4 * 4 + w;
    int b = lane >> 4, l = lane & 15;
    const int* nd = node_descs + n * DLEN;
    int idx = nd[l];
    float logit = dq[(size_t)idx * NB + b];
    float mx = logit;
#pragma unroll
    for (int off = 1; off < 16; off <<= 1) mx = fmaxf(mx, __shfl_xor(mx, off, 64));
    float e = expf(logit - mx);
    float s = e;
#pragma unroll
    for (int off = 1; off < 16; off <<= 1) s += __shfl_xor(s, off, 64);
    attn_s[w * 64 + lane] = e / s;
    if (lane < 16) idxs[w * 16 + lane] = idx;
    __syncthreads();
    float o0 = 0.f, o1 = 0.f, o2 = 0.f, o3 = 0.f;
#pragma unroll
    for (int ll = 0; ll < DLEN; ll++) {
        int row = idxs[w * 16 + ll];
        float v = __bfloat162float(descB[(size_t)row * G + lane]);
        o0 = fmaf(attn_s[w * 64 + ll], v, o0);
        o1 = fmaf(attn_s[w * 64 + 16 + ll], v, o1);
        o2 = fmaf(attn_s[w * 64 + 32 + ll], v, o2);
        o3 = fmaf(attn_s[w * 64 + 48 + ll], v, o3);
    }
    size_t baseo = (size_t)n * (NB * G) + lane;
    hb16[baseo + 0 * G] = __float2bfloat16(o0);
    hb16[baseo + 1 * G] = __float2bfloat16(o1);
    hb16[baseo + 2 * G] = __float2bfloat16(o2);
    hb16[baseo + 3 * G] = __float2bfloat16(o3);
}

__global__ __launch_bounds__(256) void k_sc_attn1(const int* flag,
                                                  const int* src, const int* dst, const int* typ,
                                                  const void* w_comp, const int* offs,
                                                  const int* rank, int2* epack,
                                                  const int* node_descs, const float* dq,
                                                  const bf16* descB, bf16* hb16) {
    __shared__ float attn_s[4 * 64];
    __shared__ int idxs[4 * DLEN];
    int bx = blockIdx.x;
    if (bx < NBLK_SCAT) {
        int e = bx * 256 + threadIdx.x;
        if (*flag) scatter_body<bf16>(e, src, dst, typ, w_comp, offs, rank, epack);
        else       scatter_body<float>(e, src, dst, typ, w_comp, offs, rank, epack);
    } else {
        int base = (bx - NBLK_SCAT) * 4;
        for (int it = 0; it < 4; it++) {
            if (it) __syncthreads();
            attn1_body(base + it, node_descs, dq, descB, hb16, attn_s, idxs);
        }
    }
}

// ---------------- RGCN aggregate fused with attn2 online-softmax partial ---
__device__ __forceinline__ void a2_update(float& M, float& L, float& A, float p, float v) {
    if (p > M) {
        float s = expf(M - p);
        A *= s; L *= s; M = p;
    }
    float e = expf(p - M);
    L += e;
    A = fmaf(e, v, A);
}

template <typename T>
__device__ void agg_body(const bf16* hb16, const int* offs, const int2* epack,
                         const void* bias_, const float* qg, float* part) {
    int tid = threadIdx.x;
    int b = tid >> 6, g = tid & 63;
    int boff = b * G + g;
    float bias = ld((const T*)bias_, (size_t)g);
    float q = qg[b * G + g];
    float M = -3.4e38f, L = 0.f, A = 0.f;
#pragma unroll 1
    for (int it = 0; it < 4; it++) {
        int dn = blockIdx.x * 4 + it;
        int s0 = offs[dn], s1 = offs[dn + 1];
        float acc = 0.f;
        int p = s0;
        for (; p + 15 < s1; p += 16) {
            int2 ev[16]; float x[16];
#pragma unroll
            for (int k = 0; k < 16; k++) ev[k] = epack[p + k];
#pragma unroll
            for (int k = 0; k < 16; k++)
                x[k] = __bfloat162float(hb16[(size_t)ev[k].x * (NB * G) + boff]);
#pragma unroll
            for (int k = 0; k < 16; k++) acc += __int_as_float(ev[k].y) * x[k];
        }
        for (; p + 7 < s1; p += 8) {
            int2 ev[8]; float x[8];
#pragma unroll
            for (int k = 0; k < 8; k++) ev[k] = epack[p + k];
#pragma unroll
            for (int k = 0; k < 8; k++)
                x[k] = __bfloat162float(hb16[(size_t)ev[k].x * (NB * G) + boff]);
#pragma unroll
            for (int k = 0; k < 8; k++) acc += __int_as_float(ev[k].y) * x[k];
        }
        for (; p + 3 < s1; p += 4) {
            int2 ev[4]; float x[4];
#pragma unroll
            for (int k = 0; k < 4; k++) ev[k] = epack[p + k];
#pragma unroll
            for (int k = 0; k < 4; k++)
                x[k] = __bfloat162float(hb16[(size_t)ev[k].x * (NB * G) + boff]);
#pragma unroll
            for (int k = 0; k < 4; k++) acc += __int_as_float(ev[k].y) * x[k];
        }
        for (; p < s1; p++) {
            int2 ev = epack[p];
            acc += __int_as_float(ev.y) * __bfloat162float(hb16[(size_t)ev.x * (NB * G) + boff]);
        }
        float v = relu(acc + bias);
        float pl = v * q;
#pragma unroll
        for (int off = 32; off >= 1; off >>= 1) pl += __shfl_xor(pl, off, 64);
        a2_update(M, L, A, pl, v);
    }
    float* pp = part + ((size_t)blockIdx.x * NB + b) * 66;
    if (g == 0) { pp[0] = M; pp[1] = L; }
    pp[2 + g] = A;
}
__global__ __launch_bounds__(256) void k_agg(const int* flag, const bf16* hb16, const int* offs,
                                             const int2* epack, const void* bias,
                                             const float* qg, float* part) {
    if (*flag) agg_body<bf16>(hb16, offs, epack, bias, qg, part);
    else       agg_body<float>(hb16, offs, epack, bias, qg, part);
}

// stage-1 merge: NPART -> A2MID partials
__global__ __launch_bounds__(256) void k_attn2m(const float* part, float* part2) {
    int tid = threadIdx.x;
    int b = tid >> 6, lane = tid & 63;
    int grp = blockIdx.x;
    const int per = (NPART + A2MID - 1) / A2MID;   // 79
    int start = grp * per;
    int end = (start + per < NPART) ? (start + per) : NPART;
    float M = -3.4e38f, L = 0.f, A = 0.f;
    for (int i = start; i < end; i++) {
        const float* pp = part + ((size_t)i * NB + b) * 66;
        float m = pp[0], l = pp[1], a = pp[2 + lane];
        float mn = fmaxf(M, m);
        float e1 = expf(M - mn), e2 = expf(m - mn);
        A = A * e1 + a * e2;
        L = L * e1 + l * e2;
        M = mn;
    }
    float* pq = part2 + ((size_t)grp * NB + b) * 66;
    if (lane == 0) { pq[0] = M; pq[1] = L; }
    pq[2 + lane] = A;
}

// ---------------- fc1 with inline final attn2 merge ----------------
template <typename T>
__device__ void fc1_body(const float* part2, const float* qemb,
                         const void* W1_, const void* b1_, float* hid,
                         float* feat, float* psum) {
    int tid = threadIdx.x;
    int b = blockIdx.x >> 4, tile = blockIdx.x & 15;
    if (tid < 64) {
        float M = -3.4e38f, L = 0.f, A = 0.f;
        for (int p = 0; p < A2MID; p++) {
            const float* pp = part2 + ((size_t)p * NB + b) * 66;
            float m = pp[0], l = pp[1], a = pp[2 + tid];
            float mn = fmaxf(M, m);
            float e1 = expf(M - mn), e2 = expf(m - mn);
            A = A * e1 + a * e2;
            L = L * e1 + l * e2;
            M = mn;
        }
        feat[tid] = A / L;
        feat[tid + 256] = qemb[b * DH + tid + 192];
    } else {
        feat[tid] = qemb[b * DH + tid - G];
    }
    __syncthreads();
    int lane = tid & 63, phase = tid >> 6;
    int u = tile * 64 + lane;
    const T* W1 = (const T*)W1_;
    float acc = 0.f;
#pragma unroll 8
    for (int kk = 0; kk < 80; kk++) {
        int k = phase * 80 + kk;
        acc += feat[k] * ld(W1, (size_t)k * 1024 + u);
    }
    psum[tid] = acc;
    __syncthreads();
    if (phase == 0) {
        float tot = psum[lane] + psum[64 + lane] + psum[128 + lane] + psum[192 + lane]
                  + ld((const T*)b1_, (size_t)u);
        hid[b * 1024 + u] = relu(tot);
    }
}
__global__ __launch_bounds__(256) void k_fc1(const int* flag, const float* part2,
                                             const float* qemb, const void* W1, const void* b1,
                                             float* hid) {
    __shared__ float feat[320];
    __shared__ float psum[256];
    if (*flag) fc1_body<bf16>(part2, qemb, W1, b1, hid, feat, psum);
    else       fc1_body<float>(part2, qemb, W1, b1, hid, feat, psum);
}

// ---------------- classifier: fc2 over transposed W2, wave-per-c ----------
template <typename T>
__device__ void fc2_body(const float* hid, const float* w2t, const void* b2_, void* out_,
                         float* hs) {
    int tid = threadIdx.x;
    for (int i = tid; i < 4096; i += 256) hs[i] = hid[i];
    __syncthreads();
    int lane = tid & 63, w = tid >> 6;
#pragma unroll
    for (int itc = 0; itc < 2; itc++) {
        int c = blockIdx.x * 8 + w * 2 + itc;
        const float* wrow = w2t + (size_t)c * 1024;
        float a0 = 0.f, a1 = 0.f, a2 = 0.f, a3 = 0.f;
#pragma unroll
        for (int i = 0; i < 16; i++) {
            int u = i * 64 + lane;
            float wv = wrow[u];
            a0 = fmaf(wv, hs[u], a0);
            a1 = fmaf(wv, hs[1024 + u], a1);
            a2 = fmaf(wv, hs[2048 + u], a2);
            a3 = fmaf(wv, hs[3072 + u], a3);
        }
#pragma unroll
        for (int off = 32; off >= 1; off >>= 1) {
            a0 += __shfl_xor(a0, off, 64);
            a1 += __shfl_xor(a1, off, 64);
            a2 += __shfl_xor(a2, off, 64);
            a3 += __shfl_xor(a3, off, 64);
        }
        if (lane < 4) {
            float av = (lane == 0) ? a0 : (lane == 1) ? a1 : (lane == 2) ? a2 : a3;
            st((T*)out_, (size_t)lane * NCLS + c, av + ld((const T*)b2_, (size_t)c));
        }
    }
}
__global__ __launch_bounds__(256) void k_fc2(const int* flag, const float* hid,
                                             const float* w2t, const void* b2v, void* out) {
    __shared__ float hs[4096];
    if (*flag) fc2_body<bf16>(hid, w2t, b2v, out, hs);
    else       fc2_body<float>(hid, w2t, b2v, out, hs);
}

extern "C" void kernel_launch(void* const* d_in, const int* in_sizes, int n_in,
                              void* d_out, int out_size, void* d_ws, size_t ws_size,
                              hipStream_t stream) {
    const int* questions  = (const int*)d_in[0];
    const int* node_descs = (const int*)d_in[1];
    const int* edge_src   = (const int*)d_in[2];
    const int* edge_dst   = (const int*)d_in[3];
    const int* edge_type  = (const int*)d_in[4];
    const void* emb_word  = d_in[5];
    const void* emb_desc  = d_in[6];
    const void* Wx_f = d_in[7];
    const void* Wh_f = d_in[8];
    const void* bx_f = d_in[9];
    const void* bh_f = d_in[10];
    const void* Wx_b = d_in[11];
    const void* Wh_b = d_in[12];
    const void* bx_b = d_in[13];
    const void* bh_b = d_in[14];
    const void* W_hg = d_in[15];
    const void* b_hg = d_in[16];
    const void* bases = d_in[17];
    const void* w_comp = d_in[18];
    const void* rgcn_bias = d_in[19];
    const void* W1 = d_in[20];
    const void* b1 = d_in[21];
    const void* W2 = d_in[22];
    const void* b2 = d_in[23];

    float* ws = (float*)d_ws;
    int*      flag  = (int*)(ws + OFF_FLAG);
    float*    gx    = ws + OFF_GX;
    float*    whf   = ws + OFF_WHF;
    float*    qemb  = ws + OFF_QEMB;
    float*    qg    = ws + OFF_QG;
    bf16*     hb16  = (bf16*)(ws + OFF_HB);
    bf16*     descB = (bf16*)(ws + OFF_DESCB);
    float*    dq    = ws + OFF_DQ;
    float*    part  = ws + OFF_PART;
    float*    part2 = ws + OFF_PART2;
    int*      deg   = (int*)(ws + OFF_DEG);
    int*      offs  = (int*)(ws + OFF_OFFS);
    int*      rank  = (int*)(ws + OFF_RANK);
    int2*     epack = (int2*)(ws + OFF_EPACK);
    float*    hid   = ws + OFF_HID;
    float*    w2t   = ws + OFF_W2T;

    hipLaunchKernelGGL(k_init, dim3(80), dim3(256), 0, stream,
                       (const unsigned*)emb_word, flag, deg);
    hipLaunchKernelGGL(k_prep,
                       dim3(NBLK_CVT + NBLK_GX2 + NBLK_DESCB + NBLK_HIST + NBLK_W2T),
                       dim3(256), 0, stream,
                       flag, Wh_f, Wh_b, whf,
                       questions, emb_word, Wx_f, bx_f, Wx_b, bx_b, gx,
                       emb_desc, bases, descB,
                       edge_dst, deg, rank, W2, w2t);
    hipLaunchKernelGGL(k_gru, dim3(9), dim3(2 * G3), 0, stream,
                       flag, questions, gx, whf, bh_f, bh_b, qemb, deg, offs);
    hipLaunchKernelGGL(k_qg_dq, dim3(1 + NBLK_DQ), dim3(256), 0, stream,
                       flag, qemb, W_hg, b_hg, qg, emb_desc, dq);
    hipLaunchKernelGGL(k_sc_attn1, dim3(NBLK_SCAT + NBLK_A1), dim3(256), 0, stream,
                       flag, edge_src, edge_dst, edge_type, w_comp, offs, rank, epack,
                       node_descs, dq, descB, hb16);
    hipLaunchKernelGGL(k_agg, dim3(NPART), dim3(256), 0, stream,
                       flag, hb16, offs, epack, rgcn_bias, qg, part);
    hipLaunchKernelGGL(k_attn2m, dim3(A2MID), dim3(256), 0, stream, part, part2);
    hipLaunchKernelGGL(k_fc1, dim3(NB * 16), dim3(256), 0, stream,
                       flag, part2, qemb, W1, b1, hid);
    hipLaunchKernelGGL(k_fc2, dim3(NCLS / 8), dim3(256), 0, stream,
                       flag, hid, w2t, b2, d_out);
}

// Round 2
// 308.210 us; speedup vs baseline: 1.0597x; 1.0597x over previous
//
#include <hip/hip_runtime.h>
#include <hip/hip_bf16.h>
#include <math.h>

typedef __hip_bfloat16 bf16;

#define NNODES 20000
#define NEDGES 320000
#define DLEN   16
#define G      64
#define DW     300
#define DH     256
#define HD     128
#define G3     384
#define NCLS   2000
#define NB     4
#define TT     32
#define VDESC  30000
#define NPART  5000   // k_agg blocks, 4 nodes each -> one attn2 partial per block
#define A2MID  64     // stage-1 merge outputs
#define MAXE   1024   // LDS-staged edges per k_agg block (avg is 64)

#define NBLK_CVT   384
#define NBLK_GX2   1536   // 256 rows (d,b,step) x 6 j-tiles of 64
#define NBLK_DESCB (VDESC / 16)            // 1875
#define NBLK_HIST  ((NEDGES + 255) / 256)
#define NBLK_W2T   (32 * 16)               // 32 c-tiles x 16 u-tiles of 64
#define NBLK_SCAT  ((NEDGES + 255) / 256)
#define NBLK_A1    (NNODES / 4)            // 1 pass, 4 nodes per block
#define NBLK_DQ    ((VDESC + 63) / 64)     // 469

__device__ __forceinline__ float ld(const float* p, size_t i) { return p[i]; }
__device__ __forceinline__ float ld(const bf16* p, size_t i) { return __bfloat162float(p[i]); }
__device__ __forceinline__ void st(float* p, size_t i, float v) { p[i] = v; }
__device__ __forceinline__ void st(bf16* p, size_t i, float v) { p[i] = __float2bfloat16(v); }
__device__ __forceinline__ float relu(float x) { return (x < 0.f) ? 0.f : x; }
__device__ __forceinline__ float bflo(unsigned u) { return __uint_as_float(u << 16); }
__device__ __forceinline__ float bfhi(unsigned u) { return __uint_as_float(u & 0xffff0000u); }

// ---------------- workspace layout (float words) ----------------
#define OFF_FLAG  ((size_t)0)                         // 4
#define OFF_GX    (OFF_FLAG + 4)                      // 98304
#define OFF_WHF   (OFF_GX   + 2*NB*TT*G3)             // 98304
#define OFF_QEMB  (OFF_WHF  + 2*HD*G3)                // 1024
#define OFF_QG    (OFF_QEMB + NB*DH)                  // 256
#define OFF_HB    (OFF_QG   + NB*G)                   // bf16 [n][b][g] = 2.56M words
#define OFF_DESCB (OFF_HB   + (size_t)NB*NNODES*G/2)  // bf16 30000*64 = 960000 words
#define OFF_DQ    (OFF_DESCB + (size_t)VDESC*G/2)     // fp32 30000*4 = 120000
#define OFF_PART  (OFF_DQ   + (size_t)VDESC*NB)       // 5000*4*66
#define OFF_PART2 (OFF_PART + (size_t)NPART*NB*66)    // 64*4*66
#define OFF_DEG   (OFF_PART2+ (size_t)A2MID*NB*66)    // int 20000
#define OFF_OFFS  (OFF_DEG  + NNODES)                 // int 20008
#define OFF_RANK  (OFF_OFFS + NNODES + 8)             // int 320000
#define OFF_EPACK (OFF_RANK + NEDGES)                 // int2 x 320000 (word idx even)
#define OFF_HID   (OFF_EPACK + 2*(size_t)NEDGES)      // 4096
#define OFF_W2T   (OFF_HID  + 4096)                   // fp32 2000*1024 = 2048000

// ---------------- init: dtype sniff + zero deg ----------------
__global__ void k_init(const unsigned* probe, int* flag, int* deg) {
    int i = blockIdx.x * 256 + threadIdx.x;
    if (i < NNODES) deg[i] = 0;
    if (blockIdx.x == 0 && threadIdx.x < 64) {
        int cnt = 0;
        for (int k = threadIdx.x; k < 4096; k += 64) {
            unsigned lo = probe[k] & 0xFFFFu;
            unsigned e = (lo >> 7) & 0xFFu;
            cnt += (e >= 0x66u && e <= 0x7Eu) ? 1 : 0;
        }
#pragma unroll
        for (int off = 1; off < 64; off <<= 1) cnt += __shfl_xor(cnt, off, 64);
        if (threadIdx.x == 0) *flag = (2 * cnt > 4096) ? 1 : 0;   // 1 = bf16
    }
}

// ---------------- fused prep: cvt | gx | descB | hist | W2 transpose -------
template <typename T>
__device__ void cvt_body(int id, const void* Whf_, const void* Whb_, float* whf) {
    if (id >= 2 * HD * G3) return;
    int d = id / (HD * G3), r = id % (HD * G3);
    const T* W = (const T*)(d ? Whb_ : Whf_);
    whf[id] = ld(W, (size_t)r);
}

template <typename T>
__device__ void gx2_body(int bx2, const int* questions, const void* emb_word_,
                         const void* Wxf_, const void* bxf_,
                         const void* Wxb_, const void* bxb_, float* gx,
                         float* xs, float* psum) {
    int tid = threadIdx.x;
    int jt = bx2 % 6;
    int rid = bx2 / 6;                  // 0..255
    int step = rid & 31;
    int b = (rid >> 5) & 3;
    int d = rid >> 7;
    int t = d ? (TT - 1 - step) : step;
    int tok = questions[b * TT + t];
    const T* row = (const T*)emb_word_ + (size_t)tok * DW;
    for (int k = tid; k < DW; k += 256) xs[k] = ld(row, (size_t)k);
    __syncthreads();
    int lane = tid & 63, phase = tid >> 6;
    int j = jt * 64 + lane;
    const T* Wx = (const T*)(d ? Wxb_ : Wxf_);
    float acc = 0.f;
    int k0 = phase * 75;
#pragma unroll 15
    for (int kk = 0; kk < 75; kk++) {
        int k = k0 + kk;
        acc += xs[k] * ld(Wx, (size_t)k * G3 + j);
    }
    psum[tid] = acc;
    __syncthreads();
    if (phase == 0) {
        const T* bx = (const T*)(d ? bxb_ : bxf_);
        float tot = ld(bx, (size_t)j)
                  + psum[lane] + psum[64 + lane] + psum[128 + lane] + psum[192 + lane];
        gx[(size_t)rid * G3 + j] = tot;
    }
}

// descB[idx][g] = sum_k emb_desc[idx][k] * bases[k][g]; 16 rows per block.
template <typename T>
__device__ void descb_body(int bx3, const void* emb_desc_, const void* bases_,
                           bf16* descB, float* bsm, float* rsm) {
    int tid = threadIdx.x;
    const T* bases = (const T*)bases_;
    const T* desc = (const T*)emb_desc_;
    for (int i = tid; i < G * G; i += 256) bsm[(i >> 6) * 68 + (i & 63)] = ld(bases, (size_t)i);
    int r0 = bx3 * 16;
    for (int i = tid; i < 16 * G; i += 256) {
        int r = i >> 6, k = i & 63;
        rsm[r * 68 + k] = ld(desc, (size_t)(r0 + r) * G + k);
    }
    __syncthreads();
    int g = tid & 63, slot = tid >> 6;
#pragma unroll
    for (int it = 0; it < 4; it++) {
        int r = slot * 4 + it;
        float acc = 0.f;
#pragma unroll 8
        for (int k = 0; k < G; k++) acc = fmaf(rsm[r * 68 + k], bsm[k * 68 + g], acc);
        descB[(size_t)(r0 + r) * G + g] = __float2bfloat16(acc);
    }
}

// transpose W2 [1024][2000] -> W2T fp32 [2000][1024] (exact copy, row-major reads in fc2)
template <typename T>
__device__ void w2t_body(int bx5, const void* W2_, float* w2t, float* tile /*64*65*/) {
    int tid = threadIdx.x;
    int ct = bx5 >> 4, ut = bx5 & 15;
    int c0 = ct * 64, u0 = ut * 64;
    int lane = tid & 63, slot = tid >> 6;
    const T* W2 = (const T*)W2_;
    int c = c0 + lane;
    bool okc = (c < NCLS);
#pragma unroll
    for (int i = 0; i < 16; i++) {
        int u = slot * 16 + i;
        tile[u * 65 + lane] = okc ? ld(W2, (size_t)(u0 + u) * NCLS + c) : 0.f;
    }
    __syncthreads();
#pragma unroll
    for (int i = 0; i < 16; i++) {
        int cl = slot * 16 + i;
        if (c0 + cl < NCLS)
            w2t[(size_t)(c0 + cl) * 1024 + u0 + lane] = tile[lane * 65 + cl];
    }
}

__global__ void k_prep(const int* flag, const void* Whf, const void* Whb, float* whf,
                       const int* questions, const void* emb_word,
                       const void* Wxf, const void* bxf,
                       const void* Wxb, const void* bxb, float* gx,
                       const void* emb_desc, const void* bases, bf16* descB,
                       const int* edge_dst, int* deg, int* rank,
                       const void* W2, float* w2t) {
    __shared__ __align__(16) float smem[64 * 68 + 16 * 68];
    int bx = blockIdx.x;
    int tid = threadIdx.x;
    if (bx < NBLK_CVT) {
        int id = bx * 256 + tid;
        if (*flag) cvt_body<bf16>(id, Whf, Whb, whf);
        else       cvt_body<float>(id, Whf, Whb, whf);
    } else if (bx < NBLK_CVT + NBLK_GX2) {
        int bx2 = bx - NBLK_CVT;
        float* xs = smem;
        float* psum = smem + 320;
        if (*flag) gx2_body<bf16>(bx2, questions, emb_word, Wxf, bxf, Wxb, bxb, gx, xs, psum);
        else       gx2_body<float>(bx2, questions, emb_word, Wxf, bxf, Wxb, bxb, gx, xs, psum);
    } else if (bx < NBLK_CVT + NBLK_GX2 + NBLK_DESCB) {
        int bx3 = bx - NBLK_CVT - NBLK_GX2;
        float* bsm = smem;
        float* rsm = smem + 64 * 68;
        if (*flag) descb_body<bf16>(bx3, emb_desc, bases, descB, bsm, rsm);
        else       descb_body<float>(bx3, emb_desc, bases, descB, bsm, rsm);
    } else if (bx < NBLK_CVT + NBLK_GX2 + NBLK_DESCB + NBLK_HIST) {
        int e = (bx - NBLK_CVT - NBLK_GX2 - NBLK_DESCB) * 256 + tid;
        if (e < NEDGES) rank[e] = atomicAdd(&deg[edge_dst[e]], 1);
    } else {
        int bx5 = bx - NBLK_CVT - NBLK_GX2 - NBLK_DESCB - NBLK_HIST;
        if (*flag) w2t_body<bf16>(bx5, W2, w2t, smem);
        else       w2t_body<float>(bx5, W2, w2t, smem);
    }
}

// ---------------- GRU scan (blocks 0..7) + CSR scan (block 8) --------------
template <typename T>
__device__ void gru_body(const int* questions, const float* gx, const float* whf,
                         const void* bhf_, const void* bhb_, float* qemb,
                         float* hsm, float* ghs) {
    int tid = threadIdx.x;
    int d = blockIdx.x >> 2, b = blockIdx.x & 3;
    int half = tid / G3, j = tid - half * G3;
    const float* wh = whf + (size_t)d * HD * G3 + (size_t)half * 64 * G3 + j;
    float w[64];
#pragma unroll
    for (int m = 0; m < 64; m++) w[m] = wh[(size_t)m * G3];
    const T* bh = (const T*)(d ? bhb_ : bhf_);
    float bhj = (half == 0) ? ld(bh, (size_t)j) : 0.f;
    if (tid < HD) hsm[tid] = 0.f;
    const float* gxb = gx + ((size_t)(d * NB + b)) * TT * G3;
    __syncthreads();
    const float4* h4 = (const float4*)(hsm + half * 64);
    for (int step = 0; step < TT; step++) {
        float acc = bhj;
#pragma unroll
        for (int m4 = 0; m4 < 16; m4++) {
            float4 hp = h4[m4];
            acc = fmaf(hp.x, w[4 * m4 + 0], acc);
            acc = fmaf(hp.y, w[4 * m4 + 1], acc);
            acc = fmaf(hp.z, w[4 * m4 + 2], acc);
            acc = fmaf(hp.w, w[4 * m4 + 3], acc);
        }
        ghs[half * G3 + j] = acc;
        __syncthreads();
        if (tid < HD) {
            const float* gxp = gxb + step * G3;
            int t = d ? (TT - 1 - step) : step;
            bool msk = questions[b * TT + t] != 0;
            float gr = ghs[tid] + ghs[G3 + tid];
            float gz = ghs[HD + tid] + ghs[G3 + HD + tid];
            float gn = ghs[2 * HD + tid] + ghs[G3 + 2 * HD + tid];
            float r = 1.f / (1.f + expf(-(gxp[tid] + gr)));
            float z = 1.f / (1.f + expf(-(gxp[HD + tid] + gz)));
            float n = tanhf(gxp[2 * HD + tid] + r * gn);
            float hn = (1.f - z) * n + z * hsm[tid];
            if (msk) hsm[tid] = hn;
        }
        __syncthreads();
    }
    if (tid < HD) qemb[b * DH + d * HD + tid] = hsm[tid];
}

// exclusive int scan of deg with 768 threads x 27 elems (exact)
__device__ void scan_body(const int* deg, int* offs, int* wtot) {
    int t = threadIdx.x;                 // 0..767
    int lane = t & 63, wave = t >> 6;    // 12 waves
    int c[27];
    int base = t * 27;
    int run = 0;
#pragma unroll
    for (int i = 0; i < 27; i++) {
        int v = (base + i < NNODES) ? deg[base + i] : 0;
        c[i] = run;
        run += v;
    }
    int myrun = run, inc = run;
#pragma unroll
    for (int off = 1; off < 64; off <<= 1) {
        int u = __shfl_up(inc, off, 64);
        if (lane >= off) inc += u;
    }
    if (lane == 63) wtot[wave] = inc;
    __syncthreads();
    if (t == 0) {
        int s = 0;
#pragma unroll
        for (int i = 0; i < 12; i++) { int v = wtot[i]; wtot[i] = s; s += v; }
        offs[NNODES] = s;
    }
    __syncthreads();
    int ebase = wtot[wave] + inc - myrun;
#pragma unroll
    for (int i = 0; i < 27; i++) {
        if (base + i < NNODES) offs[base + i] = ebase + c[i];
    }
}

__global__ __launch_bounds__(2 * G3) void k_gru(const int* flag, const int* questions,
                                                const float* gx, const float* whf,
                                                const void* bhf, const void* bhb, float* qemb,
                                                const int* deg, int* offs) {
    __shared__ __align__(16) float hsm[HD];
    __shared__ float ghs[2 * G3];
    __shared__ int wtot[12];
    if (blockIdx.x < 8) {
        if (*flag) gru_body<bf16>(questions, gx, whf, bhf, bhb, qemb, hsm, ghs);
        else       gru_body<float>(questions, gx, whf, bhf, bhb, qemb, hsm, ghs);
    } else {
        scan_body(deg, offs, wtot);
    }
}

// ---------------- qg (block 0) + dq = emb_desc @ qg^T (blocks 1..) ---------
template <typename T>
__device__ void qg_compute(const float* qemb, const void* W_hg_, const void* b_hg_,
                           float* out /*256*/) {
    int tid = threadIdx.x;
    int b = tid >> 6, g = tid & 63;
    const T* W = (const T*)W_hg_;
    float acc = ld((const T*)b_hg_, (size_t)g);
#pragma unroll 4
    for (int i = 0; i < DH; i++) acc += qemb[b * DH + i] * ld(W, (size_t)i * G + g);
    out[b * G + g] = acc;
}

template <typename T>
__device__ void dq_body(int chunk, const void* emb_desc_, const float* qgs, float* dq) {
    int tid = threadIdx.x;
    int ii = tid >> 2, b = tid & 3;
    int idx = chunk * 64 + ii;
    if (idx >= VDESC) return;
    const T* row = (const T*)emb_desc_ + (size_t)idx * G;
    const float* q = qgs + b * G;
    float acc = 0.f;
#pragma unroll 8
    for (int k = 0; k < G; k++) acc = fmaf(ld(row, (size_t)k), q[k], acc);
    dq[(size_t)idx * NB + b] = acc;
}

__global__ __launch_bounds__(256) void k_qg_dq(const int* flag, const float* qemb,
                                               const void* W_hg, const void* b_hg, float* qg,
                                               const void* emb_desc, float* dq) {
    __shared__ float qgs[NB * G];
    if (blockIdx.x == 0) {
        if (*flag) qg_compute<bf16>(qemb, W_hg, b_hg, qg);
        else       qg_compute<float>(qemb, W_hg, b_hg, qg);
        return;
    }
    // recompute qg locally (bit-identical) then fill a 64-idx dq chunk
    if (*flag) qg_compute<bf16>(qemb, W_hg, b_hg, qgs);
    else       qg_compute<float>(qemb, W_hg, b_hg, qgs);
    __syncthreads();
    int chunk = blockIdx.x - 1;
    if (*flag) dq_body<bf16>(chunk, emb_desc, qgs, dq);
    else       dq_body<float>(chunk, emb_desc, qgs, dq);
}

// ---------------- fused: scatter (no atomics) | attn1 -> hb16 directly -----
template <typename T>
__device__ void scatter_body(int e, const int* src, const int* dst, const int* typ,
                             const void* w_comp_, const int* offs, const int* rank,
                             int2* epack) {
    if (e < NEDGES) {
        int pos = offs[dst[e]] + rank[e];
        int2 v;
        v.x = src[e];
        v.y = __float_as_int(ld((const T*)w_comp_, (size_t)typ[e]));
        epack[pos] = v;
    }
}

__device__ void attn1_body(int nb4, const int* node_descs, const float* dq,
                           const bf16* descB, bf16* hb16, float* attn_s, int* idxs) {
    int tid = threadIdx.x;
    int w = tid >> 6, lane = tid & 63;
    int n = nb4 * 4 + w;
    int b = lane >> 4, l = lane & 15;
    const int* nd = node_descs + n * DLEN;
    int idx = nd[l];
    float logit = dq[(size_t)idx * NB + b];
    float mx = logit;
#pragma unroll
    for (int off = 1; off < 16; off <<= 1) mx = fmaxf(mx, __shfl_xor(mx, off, 64));
    float e = expf(logit - mx);
    float s = e;
#pragma unroll
    for (int off = 1; off < 16; off <<= 1) s += __shfl_xor(s, off, 64);
    attn_s[w * 64 + lane] = e / s;
    if (lane < 16) idxs[w * 16 + lane] = idx;
    __syncthreads();
    float o0 = 0.f, o1 = 0.f, o2 = 0.f, o3 = 0.f;
#pragma unroll
    for (int ll = 0; ll < DLEN; ll++) {
        int row = idxs[w * 16 + ll];
        float v = __bfloat162float(descB[(size_t)row * G + lane]);
        o0 = fmaf(attn_s[w * 64 + ll], v, o0);
        o1 = fmaf(attn_s[w * 64 + 16 + ll], v, o1);
        o2 = fmaf(attn_s[w * 64 + 32 + ll], v, o2);
        o3 = fmaf(attn_s[w * 64 + 48 + ll], v, o3);
    }
    size_t baseo = (size_t)n * (NB * G) + lane;
    hb16[baseo + 0 * G] = __float2bfloat16(o0);
    hb16[baseo + 1 * G] = __float2bfloat16(o1);
    hb16[baseo + 2 * G] = __float2bfloat16(o2);
    hb16[baseo + 3 * G] = __float2bfloat16(o3);
}

__global__ __launch_bounds__(256) void k_sc_attn1(const int* flag,
                                                  const int* src, const int* dst, const int* typ,
                                                  const void* w_comp, const int* offs,
                                                  const int* rank, int2* epack,
                                                  const int* node_descs, const float* dq,
                                                  const bf16* descB, bf16* hb16) {
    __shared__ float attn_s[4 * 64];
    __shared__ int idxs[4 * DLEN];
    int bx = blockIdx.x;
    if (bx < NBLK_SCAT) {
        int e = bx * 256 + threadIdx.x;
        if (*flag) scatter_body<bf16>(e, src, dst, typ, w_comp, offs, rank, epack);
        else       scatter_body<float>(e, src, dst, typ, w_comp, offs, rank, epack);
    } else {
        attn1_body(bx - NBLK_SCAT, node_descs, dq, descB, hb16, attn_s, idxs);
    }
}

// ---------------- RGCN aggregate fused with attn2 (wave = whole node) ------
// Wave lane layout: b = lane>>4, g0 = (lane&15)*4 -> 4 accumulators/lane cover
// the full [4][64] feature row; per edge ONE dwordx2 (4 bf16) per lane.
template <typename T>
__device__ void agg_body(const bf16* hb16, const int* offs, const int2* epack,
                         const void* bias_, const float* qg, float* part,
                         int2* eL, float* pm /*4*4*66*/) {
    int tid = threadIdx.x;
    int w = tid >> 6, lane = tid & 63;
    int b = lane >> 4, g0 = (lane & 15) << 2;
    int nb = blockIdx.x * 4;
    int e0 = offs[nb], e1 = offs[nb + 4];
    int ne = e1 - e0;
    int dn = nb + w;
    int s0 = offs[dn] - e0, s1 = offs[dn + 1] - e0;
    const char* hbase = (const char*)hb16 + (size_t)(b * G + g0) * 2;
    float a0 = 0.f, a1 = 0.f, a2 = 0.f, a3 = 0.f;
    for (int base = 0; base < ne; base += MAXE) {   // single pass except absurd degree
        int cnt = min(MAXE, ne - base);
        __syncthreads();
        for (int i = tid; i < cnt; i += 256) eL[i] = epack[(size_t)e0 + base + i];
        __syncthreads();
        int lo = max(s0 - base, 0), hi = min(s1 - base, cnt);
        int p = lo;
        for (; p + 7 < hi; p += 8) {
            uint2 x[8]; float wv[8];
#pragma unroll
            for (int k = 0; k < 8; k++) {
                int2 ev = eL[p + k];
                wv[k] = __int_as_float(ev.y);
                x[k] = *(const uint2*)(hbase + ((size_t)ev.x << 9));
            }
#pragma unroll
            for (int k = 0; k < 8; k++) {
                a0 = fmaf(wv[k], bflo(x[k].x), a0);
                a1 = fmaf(wv[k], bfhi(x[k].x), a1);
                a2 = fmaf(wv[k], bflo(x[k].y), a2);
                a3 = fmaf(wv[k], bfhi(x[k].y), a3);
            }
        }
        for (; p < hi; p++) {
            int2 ev = eL[p];
            float wvv = __int_as_float(ev.y);
            uint2 x = *(const uint2*)(hbase + ((size_t)ev.x << 9));
            a0 = fmaf(wvv, bflo(x.x), a0);
            a1 = fmaf(wvv, bfhi(x.x), a1);
            a2 = fmaf(wvv, bflo(x.y), a2);
            a3 = fmaf(wvv, bfhi(x.y), a3);
        }
    }
    float v0 = relu(a0 + ld((const T*)bias_, (size_t)(g0 + 0)));
    float v1 = relu(a1 + ld((const T*)bias_, (size_t)(g0 + 1)));
    float v2 = relu(a2 + ld((const T*)bias_, (size_t)(g0 + 2)));
    float v3 = relu(a3 + ld((const T*)bias_, (size_t)(g0 + 3)));
    const float* qb = qg + b * G + g0;
    float pl = v0 * qb[0] + v1 * qb[1] + v2 * qb[2] + v3 * qb[3];
#pragma unroll
    for (int off = 1; off < 16; off <<= 1) pl += __shfl_xor(pl, off, 64);
    // single-node partial: M = pl, L = 1, A = v
    float* pw = pm + (w * 4 + b) * 66;
    pw[2 + g0 + 0] = v0;
    pw[2 + g0 + 1] = v1;
    pw[2 + g0 + 2] = v2;
    pw[2 + g0 + 3] = v3;
    if ((lane & 15) == 0) { pw[0] = pl; pw[1] = 1.f; }
    __syncthreads();
    // merge the 4 node-partials (waves) for batch mb
    int mb = tid >> 6, g = tid & 63;
    float M = -3.4e38f, L = 0.f, A = 0.f;
#pragma unroll
    for (int i = 0; i < 4; i++) {
        const float* ps = pm + (i * 4 + mb) * 66;
        float m = ps[0], l = ps[1], a = ps[2 + g];
        float mn = fmaxf(M, m);
        float x1 = expf(M - mn), x2 = expf(m - mn);
        A = A * x1 + a * x2;
        L = L * x1 + l * x2;
        M = mn;
    }
    float* pp = part + ((size_t)blockIdx.x * NB + mb) * 66;
    if (g == 0) { pp[0] = M; pp[1] = L; }
    pp[2 + g] = A;
}
__global__ __launch_bounds__(256) void k_agg(const int* flag, const bf16* hb16, const int* offs,
                                             const int2* epack, const void* bias,
                                             const float* qg, float* part) {
    __shared__ int2 eL[MAXE];
    __shared__ float pm[4 * 4 * 66];
    if (*flag) agg_body<bf16>(hb16, offs, epack, bias, qg, part, eL, pm);
    else       agg_body<float>(hb16, offs, epack, bias, qg, part, eL, pm);
}

// stage-1 merge: NPART -> A2MID partials
__global__ __launch_bounds__(256) void k_attn2m(const float* part, float* part2) {
    int tid = threadIdx.x;
    int b = tid >> 6, lane = tid & 63;
    int grp = blockIdx.x;
    const int per = (NPART + A2MID - 1) / A2MID;   // 79
    int start = grp * per;
    int end = (start + per < NPART) ? (start + per) : NPART;
    float M = -3.4e38f, L = 0.f, A = 0.f;
    for (int i = start; i < end; i++) {
        const float* pp = part + ((size_t)i * NB + b) * 66;
        float m = pp[0], l = pp[1], a = pp[2 + lane];
        float mn = fmaxf(M, m);
        float e1 = expf(M - mn), e2 = expf(m - mn);
        A = A * e1 + a * e2;
        L = L * e1 + l * e2;
        M = mn;
    }
    float* pq = part2 + ((size_t)grp * NB + b) * 66;
    if (lane == 0) { pq[0] = M; pq[1] = L; }
    pq[2 + lane] = A;
}

// ---------------- fc1 with inline final attn2 merge ----------------
template <typename T>
__device__ void fc1_body(const float* part2, const float* qemb,
                         const void* W1_, const void* b1_, float* hid,
                         float* feat, float* psum) {
    int tid = threadIdx.x;
    int b = blockIdx.x >> 4, tile = blockIdx.x & 15;
    if (tid < 64) {
        float M = -3.4e38f, L = 0.f, A = 0.f;
        for (int p = 0; p < A2MID; p++) {
            const float* pp = part2 + ((size_t)p * NB + b) * 66;
            float m = pp[0], l = pp[1], a = pp[2 + tid];
            float mn = fmaxf(M, m);
            float e1 = expf(M - mn), e2 = expf(m - mn);
            A = A * e1 + a * e2;
            L = L * e1 + l * e2;
            M = mn;
        }
        feat[tid] = A / L;
        feat[tid + 256] = qemb[b * DH + tid + 192];
    } else {
        feat[tid] = qemb[b * DH + tid - G];
    }
    __syncthreads();
    int lane = tid & 63, phase = tid >> 6;
    int u = tile * 64 + lane;
    const T* W1 = (const T*)W1_;
    float acc = 0.f;
#pragma unroll 8
    for (int kk = 0; kk < 80; kk++) {
        int k = phase * 80 + kk;
        acc += feat[k] * ld(W1, (size_t)k * 1024 + u);
    }
    psum[tid] = acc;
    __syncthreads();
    if (phase == 0) {
        float tot = psum[lane] + psum[64 + lane] + psum[128 + lane] + psum[192 + lane]
                  + ld((const T*)b1_, (size_t)u);
        hid[b * 1024 + u] = relu(tot);
    }
}
__global__ __launch_bounds__(256) void k_fc1(const int* flag, const float* part2,
                                             const float* qemb, const void* W1, const void* b1,
                                             float* hid) {
    __shared__ float feat[320];
    __shared__ float psum[256];
    if (*flag) fc1_body<bf16>(part2, qemb, W1, b1, hid, feat, psum);
    else       fc1_body<float>(part2, qemb, W1, b1, hid, feat, psum);
}

// ---------------- classifier: fc2 over transposed W2, wave-per-c ----------
template <typename T>
__device__ void fc2_body(const float* hid, const float* w2t, const void* b2_, void* out_,
                         float* hs) {
    int tid = threadIdx.x;
    for (int i = tid; i < 4096; i += 256) hs[i] = hid[i];
    __syncthreads();
    int lane = tid & 63, w = tid >> 6;
#pragma unroll
    for (int itc = 0; itc < 2; itc++) {
        int c = blockIdx.x * 8 + w * 2 + itc;
        const float* wrow = w2t + (size_t)c * 1024;
        float a0 = 0.f, a1 = 0.f, a2 = 0.f, a3 = 0.f;
#pragma unroll
        for (int i = 0; i < 16; i++) {
            int u = i * 64 + lane;
            float wv = wrow[u];
            a0 = fmaf(wv, hs[u], a0);
            a1 = fmaf(wv, hs[1024 + u], a1);
            a2 = fmaf(wv, hs[2048 + u], a2);
            a3 = fmaf(wv, hs[3072 + u], a3);
        }
#pragma unroll
        for (int off = 32; off >= 1; off >>= 1) {
            a0 += __shfl_xor(a0, off, 64);
            a1 += __shfl_xor(a1, off, 64);
            a2 += __shfl_xor(a2, off, 64);
            a3 += __shfl_xor(a3, off, 64);
        }
        if (lane < 4) {
            float av = (lane == 0) ? a0 : (lane == 1) ? a1 : (lane == 2) ? a2 : a3;
            st((T*)out_, (size_t)lane * NCLS + c, av + ld((const T*)b2_, (size_t)c));
        }
    }
}
__global__ __launch_bounds__(256) void k_fc2(const int* flag, const float* hid,
                                             const float* w2t, const void* b2v, void* out) {
    __shared__ float hs[4096];
    if (*flag) fc2_body<bf16>(hid, w2t, b2v, out, hs);
    else       fc2_body<float>(hid, w2t, b2v, out, hs);
}

extern "C" void kernel_launch(void* const* d_in, const int* in_sizes, int n_in,
                              void* d_out, int out_size, void* d_ws, size_t ws_size,
                              hipStream_t stream) {
    const int* questions  = (const int*)d_in[0];
    const int* node_descs = (const int*)d_in[1];
    const int* edge_src   = (const int*)d_in[2];
    const int* edge_dst   = (const int*)d_in[3];
    const int* edge_type  = (const int*)d_in[4];
    const void* emb_word  = d_in[5];
    const void* emb_desc  = d_in[6];
    const void* Wx_f = d_in[7];
    const void* Wh_f = d_in[8];
    const void* bx_f = d_in[9];
    const void* bh_f = d_in[10];
    const void* Wx_b = d_in[11];
    const void* Wh_b = d_in[12];
    const void* bx_b = d_in[13];
    const void* bh_b = d_in[14];
    const void* W_hg = d_in[15];
    const void* b_hg = d_in[16];
    const void* bases = d_in[17];
    const void* w_comp = d_in[18];
    const void* rgcn_bias = d_in[19];
    const void* W1 = d_in[20];
    const void* b1 = d_in[21];
    const void* W2 = d_in[22];
    const void* b2 = d_in[23];

    float* ws = (float*)d_ws;
    int*      flag  = (int*)(ws + OFF_FLAG);
    float*    gx    = ws + OFF_GX;
    float*    whf   = ws + OFF_WHF;
    float*    qemb  = ws + OFF_QEMB;
    float*    qg    = ws + OFF_QG;
    bf16*     hb16  = (bf16*)(ws + OFF_HB);
    bf16*     descB = (bf16*)(ws + OFF_DESCB);
    float*    dq    = ws + OFF_DQ;
    float*    part  = ws + OFF_PART;
    float*    part2 = ws + OFF_PART2;
    int*      deg   = (int*)(ws + OFF_DEG);
    int*      offs  = (int*)(ws + OFF_OFFS);
    int*      rank  = (int*)(ws + OFF_RANK);
    int2*     epack = (int2*)(ws + OFF_EPACK);
    float*    hid   = ws + OFF_HID;
    float*    w2t   = ws + OFF_W2T;

    hipLaunchKernelGGL(k_init, dim3(80), dim3(256), 0, stream,
                       (const unsigned*)emb_word, flag, deg);
    hipLaunchKernelGGL(k_prep,
                       dim3(NBLK_CVT + NBLK_GX2 + NBLK_DESCB + NBLK_HIST + NBLK_W2T),
                       dim3(256), 0, stream,
                       flag, Wh_f, Wh_b, whf,
                       questions, emb_word, Wx_f, bx_f, Wx_b, bx_b, gx,
                       emb_desc, bases, descB,
                       edge_dst, deg, rank, W2, w2t);
    hipLaunchKernelGGL(k_gru, dim3(9), dim3(2 * G3), 0, stream,
                       flag, questions, gx, whf, bh_f, bh_b, qemb, deg, offs);
    hipLaunchKernelGGL(k_qg_dq, dim3(1 + NBLK_DQ), dim3(256), 0, stream,
                       flag, qemb, W_hg, b_hg, qg, emb_desc, dq);
    hipLaunchKernelGGL(k_sc_attn1, dim3(NBLK_SCAT + NBLK_A1), dim3(256), 0, stream,
                       flag, edge_src, edge_dst, edge_type, w_comp, offs, rank, epack,
                       node_descs, dq, descB, hb16);
    hipLaunchKernelGGL(k_agg, dim3(NPART), dim3(256), 0, stream,
                       flag, hb16, offs, epack, rgcn_bias, qg, part);
    hipLaunchKernelGGL(k_attn2m, dim3(A2MID), dim3(256), 0, stream, part, part2);
    hipLaunchKernelGGL(k_fc1, dim3(NB * 16), dim3(256), 0, stream,
                       flag, part2, qemb, W1, b1, hid);
    hipLaunchKernelGGL(k_fc2, dim3(NCLS / 8), dim3(256), 0, stream,
                       flag, hid, w2t, b2, d_out);
}